// Round 2
// 236.778 us; speedup vs baseline: 1.0254x; 1.0254x over previous
//
#include <hip/hip_runtime.h>

// Problem constants
#define B   256
#define N   100
#define D   768
#define R   80
#define RPB 8            // rows handled per block
#define THRESHOLD 0.5f

// Output layout (flat float32 offsets, in return order)
#define SZ_VIS    ((long)B * R * D)            // 15,728,640
#define OFF_VIS   0L
#define OFF_TXT   (OFF_VIS + SZ_VIS)           // 15,728,640
#define OFF_TMASK (OFF_TXT + SZ_VIS)           // 31,457,280
#define OFF_IMASK (OFF_TMASK + (long)B*(R+1))  // 31,478,016
#define OFF_RR    (OFF_IMASK + (long)B*(R+1))  // 31,498,752
#define OFF_LAB   (OFF_RR + (long)B*R)         // 31,519,232

typedef float f32x4 __attribute__((ext_vector_type(4)));

// Single fused kernel.
// grid = (R/RPB, B) = (10, 256); block = 192 threads (D/4 float4 lanes).
// Selection scan is fully parallel: threads 0..79 each classify their own
// rr element; two per-wave __ballot masks give count + stable-partition
// positions via popcount prefix (no serial thread-0 loop, no LDS rr staging).
// Big vis/txt outputs use nontemporal stores (write-once stream, never read).
__global__ __launch_bounds__(192) void fused_kernel(
    const float* __restrict__ vis,    // (B, N, 1, D)
    const float* __restrict__ txt,    // (B, N, 1, D)
    const float* __restrict__ lab_in, // (B, N)
    const float* __restrict__ rr_in,  // (B, N)
    float* __restrict__ out)
{
    const int b    = blockIdx.y;
    const int r0   = blockIdx.x * RPB;
    const int t    = threadIdx.x;
    const int lane = t & 63;
    const int wv   = t >> 6;

    __shared__ unsigned long long sel_s[2];  // selection ballot, waves 0..1
    __shared__ int                nz_s[2];   // any rr >= THRESHOLD per wave
    __shared__ int                order_s[RPB];

    // --- parallel selection scan (elements 0..79 across waves 0 and 1) ---
    float v   = 0.f;
    float lab = 0.f;
    bool  sel = false;   // binary = rr > 0.5  (drives count/order)
    bool  nzf = false;   // rr_mod nonzero <=> rr >= 0.5 (drives zero_rows)
    if (t < R) {
        v   = rr_in[b * N + t];
        if (r0 == 0) lab = lab_in[b * N + t];   // overlap with ballot/sync
        sel = (v > THRESHOLD);
        nzf = (v >= THRESHOLD);
    }
    const unsigned long long bsel = __ballot(sel);
    const unsigned long long bnz  = __ballot(nzf);
    if (wv < 2 && lane == 0) {
        sel_s[wv] = bsel;            // wave1 upper bits are 0 (t<R gate)
        nz_s[wv]  = (bnz != 0ull);
    }
    __syncthreads();

    const unsigned long long m0 = sel_s[0];
    const unsigned long long m1 = sel_s[1];
    const int cnt      = __popcll(m0) + __popcll(m1);
    const int zero_all = !(nz_s[0] | nz_s[1]);

    // stable-partition position of each selected element = prefix popcount
    if (sel) {
        const unsigned long long below = (1ull << lane) - 1ull;
        int p = (wv == 0) ? __popcll(m0 & below)
                          : __popcll(m0) + __popcll(m1 & below);
        const int rel = p - r0;
        if (rel >= 0 && rel < RPB) order_s[rel] = t;
    }
    __syncthreads();

    // --- main copy: 8 rows, thread t owns float4 column t ---
    const float* visb = vis + (long)b * N * D + t * 4;
    const float* txtb = txt + (long)b * N * D + t * 4;
    #pragma unroll
    for (int j = 0; j < RPB; ++j) {
        const int r = r0 + j;
        f32x4 vv = {0.f, 0.f, 0.f, 0.f};
        f32x4 xx = {0.f, 0.f, 0.f, 0.f};
        if (r < cnt) {                 // uniform across the block's row j
            const long ro = (long)order_s[j] * D;
            vv = *(const f32x4*)(visb + ro);
            xx = *(const f32x4*)(txtb + ro);
        }
        const long o = ((long)b * R + r) * D + t * 4;
        __builtin_nontemporal_store(vv, (f32x4*)(out + OFF_VIS + o));
        __builtin_nontemporal_store(xx, (f32x4*)(out + OFF_TXT + o));
    }

    // --- small outputs: one block per batch ---
    if (r0 == 0) {
        if (t < R) {
            out[OFF_LAB + (long)b * R + t] = lab;
            float rm = (v < THRESHOLD) ? 0.0f : v;
            if (t == 0 && zero_all) rm = 1.0f;
            out[OFF_RR + (long)b * R + t] = rm;
        }
        if (t <= R) {  // R+1 = 81 mask entries
            const float tm = (t <= cnt) ? 1.0f : 0.0f;
            out[OFF_TMASK + (long)b * (R + 1) + t] = tm;
            out[OFF_IMASK + (long)b * (R + 1) + t] = (b == B - 1) ? tm : 1.0f;
        }
    }
}

extern "C" void kernel_launch(void* const* d_in, const int* in_sizes, int n_in,
                              void* d_out, int out_size, void* d_ws, size_t ws_size,
                              hipStream_t stream) {
    // inputs (setup_inputs order):
    // 0: mean_pooling_vec (B,D)        -- unused
    // 1: merge_text_vec (B,D)          -- unused
    // 2: retrieved_visual_feature_embedding_cls (B,N,1,D)
    // 3: retrieved_textual_feature_embedding    (B,N,1,D)
    // 4: retrieved_label_list (B,N)
    // 5: RRCP (B,N)
    const float* vis = (const float*)d_in[2];
    const float* txt = (const float*)d_in[3];
    const float* lab = (const float*)d_in[4];
    const float* rr  = (const float*)d_in[5];
    float* out = (float*)d_out;

    dim3 grid(R / RPB, B);   // (10, 256)
    fused_kernel<<<grid, 192, 0, stream>>>(vis, txt, lab, rr, out);
}